// Round 4
// baseline (1394.459 us; speedup 1.0000x reference)
//
#include <hip/hip_runtime.h>

#define TPB 256
constexpr float PI_F = 3.14159265358979323846f;

constexpr int NF = 4096;           // complex FFT length (real n = 8192)
constexpr int XSTR = 4104;         // float2 stride per spectral row (4097 used)

// workspace layout (bytes) — ws_size is 256 MiB; total here ≈ 160.2 MiB
constexpr size_t XT_OFF = 0;                                     // xT [2][1024][4096] f32 = 32 MiB
constexpr size_t XF_OFF = 33554432ull;                           // Xf [2048][XSTR] float2 ≈ 64.1 MiB
constexpr size_t Y_OFF  = XF_OFF + 2048ull * XSTR * 8;           // y  [2][4][1024][4096] bf16 = 64 MiB
constexpr size_t WS_NEED = Y_OFF + 2ull * 4 * 1024 * 4096 * 2;

typedef __attribute__((ext_vector_type(8))) short bf16x8;
typedef __attribute__((ext_vector_type(4))) float f32x4;

__device__ __forceinline__ float2 cmul(float2 a, float2 b) {
    return make_float2(a.x * b.x - a.y * b.y, a.x * b.y + a.y * b.x);
}
__device__ __forceinline__ unsigned short f2bf(float f) {
    unsigned u = __float_as_uint(f);
    u += 0x7FFFu + ((u >> 16) & 1u);     // RNE; inputs finite/normal
    return (unsigned short)(u >> 16);
}
__device__ __forceinline__ float bf2f(unsigned short h) {
    return __uint_as_float((unsigned)h << 16);
}

// ---------------- radix-16 FFT machinery (N=4096 = 16^3, 3 LDS passes) ----------------
// LDS index swizzle: breaks bank aliasing for all pass access patterns (<=4-way, mostly 2-way)
__device__ __forceinline__ int PH(int j) { return j + (j >> 4) + ((j >> 8) << 2); }
// base-16 digit reversal of a 3-digit index
__device__ __forceinline__ int DR3(int q) { return ((q & 15) << 8) | (q & 240) | (q >> 8); }

__device__ __forceinline__ void tmul(float2& z, float wx, float wy) {
    z = make_float2(z.x * wx - z.y * wy, z.x * wy + z.y * wx);
}

// In-register 16-point DFT, radix-4 x radix-4. SGN=-1 fwd (e^{-i}), +1 inv.
// HZ: inputs r[8..15] are structurally zero (zero-padded data) and are not read.
// OUTPUT PERMUTATION: X[u] ends up in slot 4*(u&3) + (u>>2).
template<int SGN, bool HZ>
__device__ __forceinline__ void dft16(float2 r[16]) {
    constexpr float C1 = 0.9238795325112867f;
    constexpr float S1 = 0.3826834323650898f;
    constexpr float R2 = 0.7071067811865476f;
    const float sg = (float)SGN;
    // level 1: DFT4 over t1 within column t0 (slots t0 + 4*t1) -> A[t0][u0] at slot t0+4*u0
#pragma unroll
    for (int t0 = 0; t0 < 4; ++t0) {
        float2 a = r[t0];
        float2 b = r[t0 + 4];
        if (HZ) {
            r[t0]      = make_float2(a.x + b.x, a.y + b.y);
            r[t0 + 8]  = make_float2(a.x - b.x, a.y - b.y);
            r[t0 + 4]  = make_float2(a.x - sg * b.y, a.y + sg * b.x);  // a + SGN*i*b
            r[t0 + 12] = make_float2(a.x + sg * b.y, a.y - sg * b.x);  // a - SGN*i*b
        } else {
            float2 c = r[t0 + 8];
            float2 d = r[t0 + 12];
            float2 s0 = make_float2(a.x + c.x, a.y + c.y);
            float2 s1 = make_float2(a.x - c.x, a.y - c.y);
            float2 s2 = make_float2(b.x + d.x, b.y + d.y);
            float2 s3 = make_float2(b.x - d.x, b.y - d.y);
            r[t0]      = make_float2(s0.x + s2.x, s0.y + s2.y);
            r[t0 + 8]  = make_float2(s0.x - s2.x, s0.y - s2.y);
            r[t0 + 4]  = make_float2(s1.x - sg * s3.y, s1.y + sg * s3.x); // s1 + SGN*i*s3
            r[t0 + 12] = make_float2(s1.x + sg * s3.y, s1.y - sg * s3.x); // s1 - SGN*i*s3
        }
    }
    // twiddles W16^{t0*u0} (W(m) = (cos(m pi/8), SGN*sin(m pi/8))) on slot t0+4*u0
    tmul(r[5],  C1,  sg * S1);    // m=1
    tmul(r[9],  R2,  sg * R2);    // m=2
    tmul(r[13], S1,  sg * C1);    // m=3
    tmul(r[6],  R2,  sg * R2);    // m=2
    tmul(r[10], 0.f, sg);         // m=4
    tmul(r[14], -R2, sg * R2);    // m=6
    tmul(r[7],  S1,  sg * C1);    // m=3
    tmul(r[11], -R2, sg * R2);    // m=6
    tmul(r[15], -C1, -sg * S1);   // m=9
    // level 2: DFT4 over t0 within group u0 (slots 4*u0 + t0), in place.
    // X[u0+4*u1] -> slot 4*u0 + u1.
#pragma unroll
    for (int u0 = 0; u0 < 4; ++u0) {
        float2 a = r[4 * u0], b = r[4 * u0 + 1], c = r[4 * u0 + 2], d = r[4 * u0 + 3];
        float2 s0 = make_float2(a.x + c.x, a.y + c.y);
        float2 s1 = make_float2(a.x - c.x, a.y - c.y);
        float2 s2 = make_float2(b.x + d.x, b.y + d.y);
        float2 s3 = make_float2(b.x - d.x, b.y - d.y);
        r[4 * u0]     = make_float2(s0.x + s2.x, s0.y + s2.y);
        r[4 * u0 + 2] = make_float2(s0.x - s2.x, s0.y - s2.y);
        r[4 * u0 + 1] = make_float2(s1.x - sg * s3.y, s1.y + sg * s3.x);
        r[4 * u0 + 3] = make_float2(s1.x + sg * s3.y, s1.y - sg * s3.x);
    }
}

// Working array must hold W[q] = input[DR3(q)] before pass0. Each pass reads/writes only
// its own 16 slots -> no intra-pass sync; caller syncs BETWEEN passes.
template<int SGN, bool HZ>
__device__ __forceinline__ void fft_pass0(float2* dsh, int tid) {
    float2 r[16];
#pragma unroll
    for (int t = 0; t < (HZ ? 8 : 16); ++t) r[t] = dsh[PH(16 * tid + t)];
    dft16<SGN, HZ>(r);
#pragma unroll
    for (int u = 0; u < 16; ++u) dsh[PH(16 * tid + u)] = r[4 * (u & 3) + (u >> 2)];
}
template<int SGN>
__device__ __forceinline__ void fft_pass1(float2* dsh, int tid) {
    const int j = tid & 15;
    const int base = ((tid >> 4) << 8) + j;
    float2 r[16];
#pragma unroll
    for (int t = 0; t < 16; ++t) r[t] = dsh[PH(base + 16 * t)];
    float sv, cv;
    sincosf((float)SGN * 2.0f * PI_F * (float)j * (1.0f / 256.0f), &sv, &cv);
    float2 w = make_float2(cv, sv), wc = w;
#pragma unroll
    for (int t = 1; t < 16; ++t) { r[t] = cmul(r[t], wc); wc = cmul(wc, w); }
    dft16<SGN, false>(r);
#pragma unroll
    for (int u = 0; u < 16; ++u) dsh[PH(base + 16 * u)] = r[4 * (u & 3) + (u >> 2)];
}
template<int SGN>
__device__ __forceinline__ void fft_pass2(float2* dsh, int tid) {
    float2 r[16];
#pragma unroll
    for (int t = 0; t < 16; ++t) r[t] = dsh[PH(tid + 256 * t)];
    float sv, cv;
    sincosf((float)SGN * 2.0f * PI_F * (float)tid * (1.0f / 4096.0f), &sv, &cv);
    float2 w = make_float2(cv, sv), wc = w;
#pragma unroll
    for (int t = 1; t < 16; ++t) { r[t] = cmul(r[t], wc); wc = cmul(wc, w); }
    dft16<SGN, false>(r);
#pragma unroll
    for (int u = 0; u < 16; ++u) dsh[PH(tid + 256 * u)] = r[4 * (u & 3) + (u >> 2)];
}

// stage a zero-padded real row (as 2048 float2, digit-reversed positions) + forward FFT
__device__ __forceinline__ void fwd_fft_padded(float2* dsh, const float2* row, int tid) {
#pragma unroll
    for (int t = 0; t < 8; ++t) {
        int j = tid + (t << 8);                         // j < 2048; j>>8 == t
        dsh[PH(((j & 15) << 8) | (j & 240) | t)] = row[j];
    }
    __syncthreads();
    fft_pass0<-1, true>(dsh, tid);  __syncthreads();
    fft_pass1<-1>(dsh, tid);        __syncthreads();
    fft_pass2<-1>(dsh, tid);        __syncthreads();
}

// rfft of a length-4096 real row zero-padded to 8192, via packed 4096-pt complex FFT.
__global__ __launch_bounds__(TPB, 4) void fft_fwd(const float* __restrict__ src,
                                                  float2* __restrict__ dst) {
    __shared__ float2 dsh[4416];
    const int tid = threadIdx.x;
    const float2* x2 = (const float2*)(src + (size_t)blockIdx.x * 4096);
    fwd_fft_padded(dsh, x2, tid);
    float2* Xrow = dst + (size_t)blockIdx.x * XSTR;
#pragma unroll
    for (int t = 0; t <= 8; ++t) {
        int k = tid + (t << 8);
        if (k > 2048) break;
        float2 Zk = dsh[PH(k & (NF - 1))];
        float2 Zm = dsh[PH((NF - k) & (NF - 1))];
        float2 Fe = make_float2(0.5f * (Zk.x + Zm.x), 0.5f * (Zk.y - Zm.y));
        float2 Fo = make_float2(0.5f * (Zk.y + Zm.y), -0.5f * (Zk.x - Zm.x));
        float sv, cv;
        sincosf(-PI_F * (float)k * (1.0f / 4096.0f), &sv, &cv);
        Xrow[k] = make_float2(Fe.x + cv * Fo.x - sv * Fo.y,
                              Fe.y + cv * Fo.y + sv * Fo.x);
        if (k < 2048) {
            float2 Fe2 = make_float2(0.5f * (Zm.x + Zk.x), 0.5f * (Zm.y - Zk.y));
            float2 Fo2 = make_float2(0.5f * (Zm.y + Zk.y), -0.5f * (Zm.x - Zk.x));
            Xrow[NF - k] = make_float2(Fe2.x + (-cv) * Fo2.x - sv * Fo2.y,
                                       Fe2.y + (-cv) * Fo2.y + sv * Fo2.x);
        }
    }
}

// One block per (c,d): forward-FFT the kernel row (K spectrum -> registers),
// then for b=0,1: multiply with Xf row, packed inverse FFT, add dmat skip, write y as bf16.
__global__ __launch_bounds__(TPB, 4) void conv_fused(const float* __restrict__ kern,
                                                     const float2* __restrict__ Xf,
                                                     const float* __restrict__ xT,
                                                     const float* __restrict__ dmat,
                                                     unsigned short* __restrict__ y) {
    __shared__ float2 dsh[4416];
    const int tid = threadIdx.x;
    const int gid = blockIdx.x;              // c*1024 + d
    const int dch = gid & 1023;
    const int c = gid >> 10;

    const float2* k2 = (const float2*)(kern + (size_t)gid * 4096);
    fwd_fft_padded(dsh, k2, tid);

    // unpack K[k] / K[4096-k] into registers for exactly the freqs this thread multiplies
    float2 Kk[9], Km[9];
#pragma unroll
    for (int t = 0; t < 9; ++t) {
        int k = tid + (t << 8);
        Kk[t] = make_float2(0.f, 0.f);
        Km[t] = make_float2(0.f, 0.f);
        if (k <= 2048) {
            float2 Zk = dsh[PH(k & (NF - 1))];
            float2 Zm = dsh[PH((NF - k) & (NF - 1))];
            float2 Fe = make_float2(0.5f * (Zk.x + Zm.x), 0.5f * (Zk.y - Zm.y));
            float2 Fo = make_float2(0.5f * (Zk.y + Zm.y), -0.5f * (Zk.x - Zm.x));
            float sv, cv;
            sincosf(-PI_F * (float)k * (1.0f / 4096.0f), &sv, &cv);
            Kk[t] = make_float2(Fe.x + cv * Fo.x - sv * Fo.y,
                                Fe.y + cv * Fo.y + sv * Fo.x);
            if (k < 2048) {
                float2 Fe2 = make_float2(0.5f * (Zm.x + Zk.x), 0.5f * (Zm.y - Zk.y));
                float2 Fo2 = make_float2(0.5f * (Zm.y + Zk.y), -0.5f * (Zm.x - Zk.x));
                Km[t] = make_float2(Fe2.x + (-cv) * Fo2.x - sv * Fo2.y,
                                    Fe2.y + (-cv) * Fo2.y + sv * Fo2.x);
            } else {
                Km[t] = Kk[t];               // k == 2048 self-mirror
            }
        }
    }
    __syncthreads();                         // done reading K FFT from dsh

    const float dm = dmat[gid];
    const float sc = 1.0f / 4096.0f;
#pragma unroll 1
    for (int b = 0; b < 2; ++b) {
        const float2* Xrow = Xf + (size_t)(b * 1024 + dch) * XSTR;
        // write packed Y spectrum into digit-reversed working positions
#pragma unroll
        for (int t = 0; t < 9; ++t) {
            int k = tid + (t << 8);
            if (k > 2048) continue;
            float2 Yk = cmul(Xrow[k], Kk[t]);
            float2 Ym = cmul(Xrow[NF - k], Km[t]);
            float2 Fe = make_float2(0.5f * (Yk.x + Ym.x), 0.5f * (Yk.y - Ym.y));
            float2 G = make_float2(0.5f * (Yk.x - Ym.x), 0.5f * (Yk.y + Ym.y));
            float sv, cv;
            sincosf(PI_F * (float)k * (1.0f / 4096.0f), &sv, &cv);
            float2 Fo = make_float2(cv * G.x - sv * G.y, cv * G.y + sv * G.x);
            dsh[PH(DR3(k))] = make_float2(Fe.x - Fo.y, Fe.y + Fo.x);
            if (k > 0 && k < 2048) {         // Z[4096-k] = conj(Fe) + i*conj(Fo)
                dsh[PH(DR3(NF - k))] = make_float2(Fe.x + Fo.y, Fo.x - Fe.y);
            }
        }
        __syncthreads();
        fft_pass0<1, false>(dsh, tid); __syncthreads();
        fft_pass1<1>(dsh, tid);        __syncthreads();
        fft_pass2<1>(dsh, tid);        __syncthreads();

        const float2* x2 = (const float2*)(xT + (size_t)(b * 1024 + dch) * 4096);
        unsigned int* yrow =
            (unsigned int*)(y + (size_t)((b * 4 + c) * 1024 + dch) * 4096);
#pragma unroll
        for (int t = 0; t < 8; ++t) {
            int j = tid + (t << 8);
            float2 z = dsh[PH(j)];
            float2 xv = x2[j];
            float r0 = z.x * sc + xv.x * dm;
            float r1 = z.y * sc + xv.y * dm;
            yrow[j] = ((unsigned int)f2bf(r1) << 16) | (unsigned int)f2bf(r0);
        }
        __syncthreads();                     // y written; safe to repack dsh for next b
    }
}

// in-proj via split-bf16 MFMA, computed transposed: xT[n][l] = sum_k W[k][n]*u[m][k] + b[n].
// MFMA A = W^T (M-dim = n), B = u (N-dim = m = b*4096+l). 3 products: ah*bh + ah*bl + al*bh.
__global__ __launch_bounds__(TPB) void gemm_in_mfma(const float* __restrict__ U,
                                                    const float* __restrict__ W,
                                                    const float* __restrict__ bias,
                                                    float* __restrict__ xT) {
    __shared__ unsigned short Ah[128][40];   // [n][k] from W^T
    __shared__ unsigned short Al[128][40];
    __shared__ unsigned short Bh[128][40];   // [l][k] from U
    __shared__ unsigned short Bl[128][40];
    const int tid = threadIdx.x;
    const int n0 = blockIdx.x * 128;
    const int mo = blockIdx.y * 128;         // global m = b*4096 + l
    const int b  = mo >> 12;
    const int l0 = mo & 4095;
    const int wave = tid >> 6, lane = tid & 63;
    const int wn = (wave >> 1) * 64;         // n-dim (MFMA M)
    const int wl = (wave & 1) * 64;          // l-dim (MFMA N)
    const int fr = lane & 15, kg = lane >> 4;

    f32x4 acc[4][4];
#pragma unroll
    for (int i = 0; i < 4; ++i)
#pragma unroll
        for (int j = 0; j < 4; ++j) acc[i][j] = (f32x4){0.f, 0.f, 0.f, 0.f};

    for (int k0 = 0; k0 < 1024; k0 += 32) {
        // A staging: gather 8 k's per (n) -> bf16x8 stores (uniform banks)
#pragma unroll
        for (int r = 0; r < 2; ++r) {
            int s = tid + (r << 8);          // 0..511
            int n = s & 127, kb = s >> 7;    // kb 0..3
            const float* wp = W + (size_t)(k0 + kb * 8) * 1024 + n0 + n;
            bf16x8 h, l;
#pragma unroll
            for (int q = 0; q < 8; ++q) {
                float v = wp[(size_t)q * 1024];
                unsigned short hh = f2bf(v);
                h[q] = (short)hh;
                l[q] = (short)f2bf(v - bf2f(hh));
            }
            *(bf16x8*)&Ah[n][kb * 8] = h;
            *(bf16x8*)&Al[n][kb * 8] = l;
        }
        // B staging: float4 along k per row of U, packed u32 stores
#pragma unroll
        for (int r = 0; r < 4; ++r) {
            int s = tid + (r << 8);          // 0..1023
            int row = s >> 3, kq = (s & 7) << 2;
            float4 v = *(const float4*)(U + (size_t)(mo + row) * 1024 + k0 + kq);
            unsigned short hx = f2bf(v.x), hy = f2bf(v.y), hz = f2bf(v.z), hw = f2bf(v.w);
            unsigned short lx = f2bf(v.x - bf2f(hx)), ly = f2bf(v.y - bf2f(hy));
            unsigned short lz = f2bf(v.z - bf2f(hz)), lw = f2bf(v.w - bf2f(hw));
            *(unsigned*)&Bh[row][kq]     = (unsigned)hx | ((unsigned)hy << 16);
            *(unsigned*)&Bh[row][kq + 2] = (unsigned)hz | ((unsigned)hw << 16);
            *(unsigned*)&Bl[row][kq]     = (unsigned)lx | ((unsigned)ly << 16);
            *(unsigned*)&Bl[row][kq + 2] = (unsigned)lz | ((unsigned)lw << 16);
        }
        __syncthreads();

        bf16x8 ah[4], al[4], bh[4], bl[4];
#pragma unroll
        for (int f = 0; f < 4; ++f) {
            ah[f] = *(const bf16x8*)&Ah[wn + f * 16 + fr][kg * 8];
            al[f] = *(const bf16x8*)&Al[wn + f * 16 + fr][kg * 8];
            bh[f] = *(const bf16x8*)&Bh[wl + f * 16 + fr][kg * 8];
            bl[f] = *(const bf16x8*)&Bl[wl + f * 16 + fr][kg * 8];
        }
#pragma unroll
        for (int i = 0; i < 4; ++i)
#pragma unroll
            for (int j = 0; j < 4; ++j) {
                acc[i][j] = __builtin_amdgcn_mfma_f32_16x16x32_bf16(ah[i], bh[j], acc[i][j], 0, 0, 0);
                acc[i][j] = __builtin_amdgcn_mfma_f32_16x16x32_bf16(ah[i], bl[j], acc[i][j], 0, 0, 0);
                acc[i][j] = __builtin_amdgcn_mfma_f32_16x16x32_bf16(al[i], bh[j], acc[i][j], 0, 0, 0);
            }
        __syncthreads();
    }
#pragma unroll
    for (int i = 0; i < 4; ++i)
#pragma unroll
        for (int j = 0; j < 4; ++j)
#pragma unroll
            for (int rr = 0; rr < 4; ++rr) {
                int ng = n0 + wn + i * 16 + kg * 4 + rr;   // C/D row
                int lg = l0 + wl + j * 16 + fr;            // C/D col
                xT[(size_t)(b * 1024 + ng) * 4096 + lg] = acc[i][j][rr] + bias[ng];
            }
}

// out-proj: out[m][n] = sum_k y[b][k][l]*W[k][n] + bias[n]. A = bf16 y, B = fp32 W split hi/lo.
__global__ __launch_bounds__(TPB) void gemm_out_mfma(const unsigned short* __restrict__ Y,
                                                     const float* __restrict__ W,
                                                     const float* __restrict__ bias,
                                                     float* __restrict__ out) {
    __shared__ unsigned short Ah[128][40];   // [m(l)][k]
    __shared__ unsigned short Bh[128][40];   // [n][k]
    __shared__ unsigned short Bl[128][40];
    const int tid = threadIdx.x;
    const int m0 = blockIdx.x * 128;         // over M = 8192 (b*4096 + l)
    const int n0 = blockIdx.y * 128;
    const int b = m0 >> 12;
    const size_t kbase = (size_t)b * 4096;
    const int wave = tid >> 6, lane = tid & 63;
    const int wm = (wave >> 1) * 64;
    const int wn = (wave & 1) * 64;
    const int fr = lane & 15, kg = lane >> 4;

    f32x4 acc[4][4];
#pragma unroll
    for (int i = 0; i < 4; ++i)
#pragma unroll
        for (int j = 0; j < 4; ++j) acc[i][j] = (f32x4){0.f, 0.f, 0.f, 0.f};

    for (int k0 = 0; k0 < 4096; k0 += 32) {
#pragma unroll
        for (int r = 0; r < 2; ++r) {
            int s = tid + (r << 8);          // 0..511
            int li = s & 127;
            int kb = s >> 7;                 // 0..3 (8 k's each)
            {
                const unsigned short* ap =
                    Y + (kbase + k0 + kb * 8) * 4096 + (m0 & 4095) + li;
                bf16x8 h;
#pragma unroll
                for (int i = 0; i < 8; ++i) h[i] = (short)ap[(size_t)i * 4096];
                *(bf16x8*)&Ah[li][kb * 8] = h;
            }
            {
                const float* wp = W + (size_t)(k0 + kb * 8) * 1024 + n0 + li;
                bf16x8 h, l8;
#pragma unroll
                for (int i = 0; i < 8; ++i) {
                    float v = wp[(size_t)i * 1024];
                    unsigned short hh = f2bf(v);
                    h[i] = (short)hh;
                    l8[i] = (short)f2bf(v - bf2f(hh));
                }
                *(bf16x8*)&Bh[li][kb * 8] = h;
                *(bf16x8*)&Bl[li][kb * 8] = l8;
            }
        }
        __syncthreads();

        bf16x8 ah[4], bh[4], bl[4];
#pragma unroll
        for (int f = 0; f < 4; ++f) {
            ah[f] = *(const bf16x8*)&Ah[wm + f * 16 + fr][kg * 8];
            bh[f] = *(const bf16x8*)&Bh[wn + f * 16 + fr][kg * 8];
            bl[f] = *(const bf16x8*)&Bl[wn + f * 16 + fr][kg * 8];
        }
#pragma unroll
        for (int i = 0; i < 4; ++i)
#pragma unroll
            for (int j = 0; j < 4; ++j) {
                acc[i][j] = __builtin_amdgcn_mfma_f32_16x16x32_bf16(ah[i], bh[j], acc[i][j], 0, 0, 0);
                acc[i][j] = __builtin_amdgcn_mfma_f32_16x16x32_bf16(ah[i], bl[j], acc[i][j], 0, 0, 0);
            }
        __syncthreads();
    }

    float bj[4];
#pragma unroll
    for (int j = 0; j < 4; ++j) bj[j] = bias[n0 + wn + j * 16 + fr];
#pragma unroll
    for (int i = 0; i < 4; ++i)
#pragma unroll
        for (int j = 0; j < 4; ++j)
#pragma unroll
            for (int r = 0; r < 4; ++r) {
                int m = m0 + wm + i * 16 + kg * 4 + r;
                int n = n0 + wn + j * 16 + fr;
                out[(size_t)m * 1024 + n] = acc[i][j][r] + bj[j];
            }
}

__global__ void ws_fail(float* out, float wssz) {
    out[0] = -12345.0f;
    out[1] = wssz;
}

extern "C" void kernel_launch(void* const* d_in, const int* in_sizes, int n_in,
                              void* d_out, int out_size, void* d_ws, size_t ws_size,
                              hipStream_t stream) {
    (void)in_sizes; (void)n_in; (void)out_size;
    float* out = (float*)d_out;
    if (ws_size < WS_NEED) {                 // sentinel: reports ws_size via validation mismatch
        ws_fail<<<1, 1, 0, stream>>>(out, (float)ws_size);
        return;
    }

    const float* u    = (const float*)d_in[0];
    const float* in_w = (const float*)d_in[1];
    const float* in_b = (const float*)d_in[2];
    const float* kern = (const float*)d_in[3];
    const float* dmat = (const float*)d_in[4];
    const float* outw = (const float*)d_in[5];
    const float* outb = (const float*)d_in[6];

    char* ws = (char*)d_ws;
    float*          xT = (float*)(ws + XT_OFF);
    float2*         Xf = (float2*)(ws + XF_OFF);
    unsigned short* y  = (unsigned short*)(ws + Y_OFF);

    gemm_in_mfma<<<dim3(8, 64), TPB, 0, stream>>>(u, in_w, in_b, xT);
    fft_fwd<<<dim3(2048), TPB, 0, stream>>>(xT, Xf);
    conv_fused<<<dim3(4096), TPB, 0, stream>>>(kern, Xf, xT, dmat, y);
    gemm_out_mfma<<<dim3(64, 8), TPB, 0, stream>>>(y, outw, outb, out);
}

// Round 5
// 776.032 us; speedup vs baseline: 1.7969x; 1.7969x over previous
//
#include <hip/hip_runtime.h>

#define TPB 256
constexpr float PI_F = 3.14159265358979323846f;

constexpr int NF = 4096;           // complex FFT length (real n = 8192)
constexpr int XSTR = 4104;         // float2 stride per spectral row (4097 used)

// workspace layout (bytes) — ws_size is 256 MiB; total here ≈ 160.2 MiB
constexpr size_t XT_OFF = 0;                                     // xT [2][1024][4096] f32 = 32 MiB
constexpr size_t XF_OFF = 33554432ull;                           // Xf [2048][XSTR] float2 ≈ 64.1 MiB
constexpr size_t Y_OFF  = XF_OFF + 2048ull * XSTR * 8;           // y  [2][4][1024][4096] bf16 = 64 MiB
constexpr size_t WS_NEED = Y_OFF + 2ull * 4 * 1024 * 4096 * 2;

typedef __attribute__((ext_vector_type(8))) short bf16x8;
typedef __attribute__((ext_vector_type(4))) float f32x4;

__device__ __forceinline__ float2 cmul(float2 a, float2 b) {
    return make_float2(a.x * b.x - a.y * b.y, a.x * b.y + a.y * b.x);
}
__device__ __forceinline__ unsigned short f2bf(float f) {
    unsigned u = __float_as_uint(f);
    u += 0x7FFFu + ((u >> 16) & 1u);     // RNE; inputs finite/normal
    return (unsigned short)(u >> 16);
}
__device__ __forceinline__ float bf2f(unsigned short h) {
    return __uint_as_float((unsigned)h << 16);
}

// ---------------- radix-16 FFT machinery (N=4096 = 16^3, 3 LDS passes) ----------------
// LDS index swizzle: breaks bank aliasing for all pass access patterns (<=4-way, mostly 2-way)
__device__ __forceinline__ int PH(int j) { return j + (j >> 4) + ((j >> 8) << 2); }
// base-16 digit reversal of a 3-digit index
__device__ __forceinline__ int DR3(int q) { return ((q & 15) << 8) | (q & 240) | (q >> 8); }

__device__ __forceinline__ void tmul(float2& z, float wx, float wy) {
    z = make_float2(z.x * wx - z.y * wy, z.x * wy + z.y * wx);
}

// In-register 16-point DFT, radix-4 x radix-4. SGN=-1 fwd (e^{-i}), +1 inv.
// HZ: inputs r[8..15] are structurally zero (zero-padded data) and are not read.
// OUTPUT PERMUTATION: X[u] ends up in slot 4*(u&3) + (u>>2).
template<int SGN, bool HZ>
__device__ __forceinline__ void dft16(float2 r[16]) {
    constexpr float C1 = 0.9238795325112867f;
    constexpr float S1 = 0.3826834323650898f;
    constexpr float R2 = 0.7071067811865476f;
    const float sg = (float)SGN;
    // level 1: DFT4 over t1 within column t0 (slots t0 + 4*t1) -> A[t0][u0] at slot t0+4*u0
#pragma unroll
    for (int t0 = 0; t0 < 4; ++t0) {
        float2 a = r[t0];
        float2 b = r[t0 + 4];
        if (HZ) {
            r[t0]      = make_float2(a.x + b.x, a.y + b.y);
            r[t0 + 8]  = make_float2(a.x - b.x, a.y - b.y);
            r[t0 + 4]  = make_float2(a.x - sg * b.y, a.y + sg * b.x);  // a + SGN*i*b
            r[t0 + 12] = make_float2(a.x + sg * b.y, a.y - sg * b.x);  // a - SGN*i*b
        } else {
            float2 c = r[t0 + 8];
            float2 d = r[t0 + 12];
            float2 s0 = make_float2(a.x + c.x, a.y + c.y);
            float2 s1 = make_float2(a.x - c.x, a.y - c.y);
            float2 s2 = make_float2(b.x + d.x, b.y + d.y);
            float2 s3 = make_float2(b.x - d.x, b.y - d.y);
            r[t0]      = make_float2(s0.x + s2.x, s0.y + s2.y);
            r[t0 + 8]  = make_float2(s0.x - s2.x, s0.y - s2.y);
            r[t0 + 4]  = make_float2(s1.x - sg * s3.y, s1.y + sg * s3.x); // s1 + SGN*i*s3
            r[t0 + 12] = make_float2(s1.x + sg * s3.y, s1.y - sg * s3.x); // s1 - SGN*i*s3
        }
    }
    // twiddles W16^{t0*u0} (W(m) = (cos(m pi/8), SGN*sin(m pi/8))) on slot t0+4*u0
    tmul(r[5],  C1,  sg * S1);    // m=1
    tmul(r[9],  R2,  sg * R2);    // m=2
    tmul(r[13], S1,  sg * C1);    // m=3
    tmul(r[6],  R2,  sg * R2);    // m=2
    tmul(r[10], 0.f, sg);         // m=4
    tmul(r[14], -R2, sg * R2);    // m=6
    tmul(r[7],  S1,  sg * C1);    // m=3
    tmul(r[11], -R2, sg * R2);    // m=6
    tmul(r[15], -C1, -sg * S1);   // m=9
    // level 2: DFT4 over t0 within group u0 (slots 4*u0 + t0), in place.
    // X[u0+4*u1] -> slot 4*u0 + u1.
#pragma unroll
    for (int u0 = 0; u0 < 4; ++u0) {
        float2 a = r[4 * u0], b = r[4 * u0 + 1], c = r[4 * u0 + 2], d = r[4 * u0 + 3];
        float2 s0 = make_float2(a.x + c.x, a.y + c.y);
        float2 s1 = make_float2(a.x - c.x, a.y - c.y);
        float2 s2 = make_float2(b.x + d.x, b.y + d.y);
        float2 s3 = make_float2(b.x - d.x, b.y - d.y);
        r[4 * u0]     = make_float2(s0.x + s2.x, s0.y + s2.y);
        r[4 * u0 + 2] = make_float2(s0.x - s2.x, s0.y - s2.y);
        r[4 * u0 + 1] = make_float2(s1.x - sg * s3.y, s1.y + sg * s3.x);
        r[4 * u0 + 3] = make_float2(s1.x + sg * s3.y, s1.y - sg * s3.x);
    }
}

// Working array must hold W[q] = input[DR3(q)] before pass0. Each pass reads/writes only
// its own 16 slots -> no intra-pass sync; caller syncs BETWEEN passes.
template<int SGN, bool HZ>
__device__ __forceinline__ void fft_pass0(float2* dsh, int tid) {
    float2 r[16];
#pragma unroll
    for (int t = 0; t < (HZ ? 8 : 16); ++t) r[t] = dsh[PH(16 * tid + t)];
    dft16<SGN, HZ>(r);
#pragma unroll
    for (int u = 0; u < 16; ++u) dsh[PH(16 * tid + u)] = r[4 * (u & 3) + (u >> 2)];
}
template<int SGN>
__device__ __forceinline__ void fft_pass1(float2* dsh, int tid) {
    const int j = tid & 15;
    const int base = ((tid >> 4) << 8) + j;
    float2 r[16];
#pragma unroll
    for (int t = 0; t < 16; ++t) r[t] = dsh[PH(base + 16 * t)];
    float sv, cv;
    sincosf((float)SGN * 2.0f * PI_F * (float)j * (1.0f / 256.0f), &sv, &cv);
    float2 w = make_float2(cv, sv), wc = w;
#pragma unroll
    for (int t = 1; t < 16; ++t) { r[t] = cmul(r[t], wc); wc = cmul(wc, w); }
    dft16<SGN, false>(r);
#pragma unroll
    for (int u = 0; u < 16; ++u) dsh[PH(base + 16 * u)] = r[4 * (u & 3) + (u >> 2)];
}
template<int SGN>
__device__ __forceinline__ void fft_pass2(float2* dsh, int tid) {
    float2 r[16];
#pragma unroll
    for (int t = 0; t < 16; ++t) r[t] = dsh[PH(tid + 256 * t)];
    float sv, cv;
    sincosf((float)SGN * 2.0f * PI_F * (float)tid * (1.0f / 4096.0f), &sv, &cv);
    float2 w = make_float2(cv, sv), wc = w;
#pragma unroll
    for (int t = 1; t < 16; ++t) { r[t] = cmul(r[t], wc); wc = cmul(wc, w); }
    dft16<SGN, false>(r);
#pragma unroll
    for (int u = 0; u < 16; ++u) dsh[PH(tid + 256 * u)] = r[4 * (u & 3) + (u >> 2)];
}

// stage a zero-padded real row (as 2048 float2, digit-reversed positions) + forward FFT
__device__ __forceinline__ void fwd_fft_padded(float2* dsh, const float2* row, int tid) {
#pragma unroll
    for (int t = 0; t < 8; ++t) {
        int j = tid + (t << 8);                         // j < 2048; j>>8 == t
        dsh[PH(((j & 15) << 8) | (j & 240) | t)] = row[j];
    }
    __syncthreads();
    fft_pass0<-1, true>(dsh, tid);  __syncthreads();
    fft_pass1<-1>(dsh, tid);        __syncthreads();
    fft_pass2<-1>(dsh, tid);        __syncthreads();
}

// rfft of a length-4096 real row zero-padded to 8192, via packed 4096-pt complex FFT.
__global__ __launch_bounds__(TPB) void fft_fwd(const float* __restrict__ src,
                                               float2* __restrict__ dst) {
    __shared__ float2 dsh[4416];
    const int tid = threadIdx.x;
    const float2* x2 = (const float2*)(src + (size_t)blockIdx.x * 4096);
    fwd_fft_padded(dsh, x2, tid);
    float2* Xrow = dst + (size_t)blockIdx.x * XSTR;
#pragma unroll
    for (int t = 0; t <= 8; ++t) {
        int k = tid + (t << 8);
        if (k > 2048) break;
        float2 Zk = dsh[PH(k & (NF - 1))];
        float2 Zm = dsh[PH((NF - k) & (NF - 1))];
        float2 Fe = make_float2(0.5f * (Zk.x + Zm.x), 0.5f * (Zk.y - Zm.y));
        float2 Fo = make_float2(0.5f * (Zk.y + Zm.y), -0.5f * (Zk.x - Zm.x));
        float sv, cv;
        sincosf(-PI_F * (float)k * (1.0f / 4096.0f), &sv, &cv);
        Xrow[k] = make_float2(Fe.x + cv * Fo.x - sv * Fo.y,
                              Fe.y + cv * Fo.y + sv * Fo.x);
        if (k < 2048) {
            float2 Fe2 = make_float2(0.5f * (Zm.x + Zk.x), 0.5f * (Zm.y - Zk.y));
            float2 Fo2 = make_float2(0.5f * (Zm.y + Zk.y), -0.5f * (Zm.x - Zk.x));
            Xrow[NF - k] = make_float2(Fe2.x + (-cv) * Fo2.x - sv * Fo2.y,
                                       Fe2.y + (-cv) * Fo2.y + sv * Fo2.x);
        }
    }
}

// One block per (c,d): forward-FFT the kernel row (K spectrum -> registers),
// then for b=0,1: multiply with Xf row, packed inverse FFT, add dmat skip, write y as bf16.
__global__ __launch_bounds__(TPB) void conv_fused(const float* __restrict__ kern,
                                                  const float2* __restrict__ Xf,
                                                  const float* __restrict__ xT,
                                                  const float* __restrict__ dmat,
                                                  unsigned short* __restrict__ y) {
    __shared__ float2 dsh[4416];
    const int tid = threadIdx.x;
    const int gid = blockIdx.x;              // c*1024 + d
    const int dch = gid & 1023;
    const int c = gid >> 10;

    const float2* k2 = (const float2*)(kern + (size_t)gid * 4096);
    fwd_fft_padded(dsh, k2, tid);

    // unpack K[k] / K[4096-k] into registers for exactly the freqs this thread multiplies
    float2 Kk[9], Km[9];
#pragma unroll
    for (int t = 0; t < 9; ++t) {
        int k = tid + (t << 8);
        Kk[t] = make_float2(0.f, 0.f);
        Km[t] = make_float2(0.f, 0.f);
        if (k <= 2048) {
            float2 Zk = dsh[PH(k & (NF - 1))];
            float2 Zm = dsh[PH((NF - k) & (NF - 1))];
            float2 Fe = make_float2(0.5f * (Zk.x + Zm.x), 0.5f * (Zk.y - Zm.y));
            float2 Fo = make_float2(0.5f * (Zk.y + Zm.y), -0.5f * (Zk.x - Zm.x));
            float sv, cv;
            sincosf(-PI_F * (float)k * (1.0f / 4096.0f), &sv, &cv);
            Kk[t] = make_float2(Fe.x + cv * Fo.x - sv * Fo.y,
                                Fe.y + cv * Fo.y + sv * Fo.x);
            if (k < 2048) {
                float2 Fe2 = make_float2(0.5f * (Zm.x + Zk.x), 0.5f * (Zm.y - Zk.y));
                float2 Fo2 = make_float2(0.5f * (Zm.y + Zk.y), -0.5f * (Zm.x - Zk.x));
                Km[t] = make_float2(Fe2.x + (-cv) * Fo2.x - sv * Fo2.y,
                                    Fe2.y + (-cv) * Fo2.y + sv * Fo2.x);
            } else {
                Km[t] = Kk[t];               // k == 2048 self-mirror
            }
        }
    }
    __syncthreads();                         // done reading K FFT from dsh

    const float dm = dmat[gid];
    const float sc = 1.0f / 4096.0f;
#pragma unroll 1
    for (int b = 0; b < 2; ++b) {
        const float2* Xrow = Xf + (size_t)(b * 1024 + dch) * XSTR;
        // write packed Y spectrum into digit-reversed working positions
#pragma unroll
        for (int t = 0; t < 9; ++t) {
            int k = tid + (t << 8);
            if (k > 2048) continue;
            float2 Yk = cmul(Xrow[k], Kk[t]);
            float2 Ym = cmul(Xrow[NF - k], Km[t]);
            float2 Fe = make_float2(0.5f * (Yk.x + Ym.x), 0.5f * (Yk.y - Ym.y));
            float2 G = make_float2(0.5f * (Yk.x - Ym.x), 0.5f * (Yk.y + Ym.y));
            float sv, cv;
            sincosf(PI_F * (float)k * (1.0f / 4096.0f), &sv, &cv);
            float2 Fo = make_float2(cv * G.x - sv * G.y, cv * G.y + sv * G.x);
            dsh[PH(DR3(k))] = make_float2(Fe.x - Fo.y, Fe.y + Fo.x);
            if (k > 0 && k < 2048) {         // Z[4096-k] = conj(Fe) + i*conj(Fo)
                dsh[PH(DR3(NF - k))] = make_float2(Fe.x + Fo.y, Fo.x - Fe.y);
            }
        }
        __syncthreads();
        fft_pass0<1, false>(dsh, tid); __syncthreads();
        fft_pass1<1>(dsh, tid);        __syncthreads();
        fft_pass2<1>(dsh, tid);        __syncthreads();

        const float2* x2 = (const float2*)(xT + (size_t)(b * 1024 + dch) * 4096);
        unsigned int* yrow =
            (unsigned int*)(y + (size_t)((b * 4 + c) * 1024 + dch) * 4096);
#pragma unroll
        for (int t = 0; t < 8; ++t) {
            int j = tid + (t << 8);
            float2 z = dsh[PH(j)];
            float2 xv = x2[j];
            float r0 = z.x * sc + xv.x * dm;
            float r1 = z.y * sc + xv.y * dm;
            yrow[j] = ((unsigned int)f2bf(r1) << 16) | (unsigned int)f2bf(r0);
        }
        __syncthreads();                     // y written; safe to repack dsh for next b
    }
}

// in-proj via split-bf16 MFMA, computed transposed: xT[n][l] = sum_k W[k][n]*u[m][k] + b[n].
// MFMA A = W^T (M-dim = n), B = u (N-dim = m = b*4096+l). 3 products: ah*bh + ah*bl + al*bh.
__global__ __launch_bounds__(TPB) void gemm_in_mfma(const float* __restrict__ U,
                                                    const float* __restrict__ W,
                                                    const float* __restrict__ bias,
                                                    float* __restrict__ xT) {
    __shared__ unsigned short Ah[128][40];   // [n][k] from W^T
    __shared__ unsigned short Al[128][40];
    __shared__ unsigned short Bh[128][40];   // [l][k] from U
    __shared__ unsigned short Bl[128][40];
    const int tid = threadIdx.x;
    const int n0 = blockIdx.x * 128;
    const int mo = blockIdx.y * 128;         // global m = b*4096 + l
    const int b  = mo >> 12;
    const int l0 = mo & 4095;
    const int wave = tid >> 6, lane = tid & 63;
    const int wn = (wave >> 1) * 64;         // n-dim (MFMA M)
    const int wl = (wave & 1) * 64;          // l-dim (MFMA N)
    const int fr = lane & 15, kg = lane >> 4;

    f32x4 acc[4][4];
#pragma unroll
    for (int i = 0; i < 4; ++i)
#pragma unroll
        for (int j = 0; j < 4; ++j) acc[i][j] = (f32x4){0.f, 0.f, 0.f, 0.f};

    for (int k0 = 0; k0 < 1024; k0 += 32) {
        // A staging: gather 8 k's per (n) -> bf16x8 stores (uniform banks)
#pragma unroll
        for (int r = 0; r < 2; ++r) {
            int s = tid + (r << 8);          // 0..511
            int n = s & 127, kb = s >> 7;    // kb 0..3
            const float* wp = W + (size_t)(k0 + kb * 8) * 1024 + n0 + n;
            bf16x8 h, l;
#pragma unroll
            for (int q = 0; q < 8; ++q) {
                float v = wp[(size_t)q * 1024];
                unsigned short hh = f2bf(v);
                h[q] = (short)hh;
                l[q] = (short)f2bf(v - bf2f(hh));
            }
            *(bf16x8*)&Ah[n][kb * 8] = h;
            *(bf16x8*)&Al[n][kb * 8] = l;
        }
        // B staging: float4 along k per row of U, packed u32 stores
#pragma unroll
        for (int r = 0; r < 4; ++r) {
            int s = tid + (r << 8);          // 0..1023
            int row = s >> 3, kq = (s & 7) << 2;
            float4 v = *(const float4*)(U + (size_t)(mo + row) * 1024 + k0 + kq);
            unsigned short hx = f2bf(v.x), hy = f2bf(v.y), hz = f2bf(v.z), hw = f2bf(v.w);
            unsigned short lx = f2bf(v.x - bf2f(hx)), ly = f2bf(v.y - bf2f(hy));
            unsigned short lz = f2bf(v.z - bf2f(hz)), lw = f2bf(v.w - bf2f(hw));
            *(unsigned*)&Bh[row][kq]     = (unsigned)hx | ((unsigned)hy << 16);
            *(unsigned*)&Bh[row][kq + 2] = (unsigned)hz | ((unsigned)hw << 16);
            *(unsigned*)&Bl[row][kq]     = (unsigned)lx | ((unsigned)ly << 16);
            *(unsigned*)&Bl[row][kq + 2] = (unsigned)lz | ((unsigned)lw << 16);
        }
        __syncthreads();

        bf16x8 ah[4], al[4], bh[4], bl[4];
#pragma unroll
        for (int f = 0; f < 4; ++f) {
            ah[f] = *(const bf16x8*)&Ah[wn + f * 16 + fr][kg * 8];
            al[f] = *(const bf16x8*)&Al[wn + f * 16 + fr][kg * 8];
            bh[f] = *(const bf16x8*)&Bh[wl + f * 16 + fr][kg * 8];
            bl[f] = *(const bf16x8*)&Bl[wl + f * 16 + fr][kg * 8];
        }
#pragma unroll
        for (int i = 0; i < 4; ++i)
#pragma unroll
            for (int j = 0; j < 4; ++j) {
                acc[i][j] = __builtin_amdgcn_mfma_f32_16x16x32_bf16(ah[i], bh[j], acc[i][j], 0, 0, 0);
                acc[i][j] = __builtin_amdgcn_mfma_f32_16x16x32_bf16(ah[i], bl[j], acc[i][j], 0, 0, 0);
                acc[i][j] = __builtin_amdgcn_mfma_f32_16x16x32_bf16(al[i], bh[j], acc[i][j], 0, 0, 0);
            }
        __syncthreads();
    }
#pragma unroll
    for (int i = 0; i < 4; ++i)
#pragma unroll
        for (int j = 0; j < 4; ++j)
#pragma unroll
            for (int rr = 0; rr < 4; ++rr) {
                int ng = n0 + wn + i * 16 + kg * 4 + rr;   // C/D row
                int lg = l0 + wl + j * 16 + fr;            // C/D col
                xT[(size_t)(b * 1024 + ng) * 4096 + lg] = acc[i][j][rr] + bias[ng];
            }
}

// out-proj: out[m][n] = sum_k y[b][k][l]*W[k][n] + bias[n]. A = bf16 y, B = fp32 W split hi/lo.
__global__ __launch_bounds__(TPB) void gemm_out_mfma(const unsigned short* __restrict__ Y,
                                                     const float* __restrict__ W,
                                                     const float* __restrict__ bias,
                                                     float* __restrict__ out) {
    __shared__ unsigned short Ah[128][40];   // [m(l)][k]
    __shared__ unsigned short Bh[128][40];   // [n][k]
    __shared__ unsigned short Bl[128][40];
    const int tid = threadIdx.x;
    const int m0 = blockIdx.x * 128;         // over M = 8192 (b*4096 + l)
    const int n0 = blockIdx.y * 128;
    const int b = m0 >> 12;
    const size_t kbase = (size_t)b * 4096;
    const int wave = tid >> 6, lane = tid & 63;
    const int wm = (wave >> 1) * 64;
    const int wn = (wave & 1) * 64;
    const int fr = lane & 15, kg = lane >> 4;

    f32x4 acc[4][4];
#pragma unroll
    for (int i = 0; i < 4; ++i)
#pragma unroll
        for (int j = 0; j < 4; ++j) acc[i][j] = (f32x4){0.f, 0.f, 0.f, 0.f};

    for (int k0 = 0; k0 < 4096; k0 += 32) {
#pragma unroll
        for (int r = 0; r < 2; ++r) {
            int s = tid + (r << 8);          // 0..511
            int li = s & 127;
            int kb = s >> 7;                 // 0..3 (8 k's each)
            {
                const unsigned short* ap =
                    Y + (kbase + k0 + kb * 8) * 4096 + (m0 & 4095) + li;
                bf16x8 h;
#pragma unroll
                for (int i = 0; i < 8; ++i) h[i] = (short)ap[(size_t)i * 4096];
                *(bf16x8*)&Ah[li][kb * 8] = h;
            }
            {
                const float* wp = W + (size_t)(k0 + kb * 8) * 1024 + n0 + li;
                bf16x8 h, l8;
#pragma unroll
                for (int i = 0; i < 8; ++i) {
                    float v = wp[(size_t)i * 1024];
                    unsigned short hh = f2bf(v);
                    h[i] = (short)hh;
                    l8[i] = (short)f2bf(v - bf2f(hh));
                }
                *(bf16x8*)&Bh[li][kb * 8] = h;
                *(bf16x8*)&Bl[li][kb * 8] = l8;
            }
        }
        __syncthreads();

        bf16x8 ah[4], bh[4], bl[4];
#pragma unroll
        for (int f = 0; f < 4; ++f) {
            ah[f] = *(const bf16x8*)&Ah[wm + f * 16 + fr][kg * 8];
            bh[f] = *(const bf16x8*)&Bh[wn + f * 16 + fr][kg * 8];
            bl[f] = *(const bf16x8*)&Bl[wn + f * 16 + fr][kg * 8];
        }
#pragma unroll
        for (int i = 0; i < 4; ++i)
#pragma unroll
            for (int j = 0; j < 4; ++j) {
                acc[i][j] = __builtin_amdgcn_mfma_f32_16x16x32_bf16(ah[i], bh[j], acc[i][j], 0, 0, 0);
                acc[i][j] = __builtin_amdgcn_mfma_f32_16x16x32_bf16(ah[i], bl[j], acc[i][j], 0, 0, 0);
            }
        __syncthreads();
    }

    float bj[4];
#pragma unroll
    for (int j = 0; j < 4; ++j) bj[j] = bias[n0 + wn + j * 16 + fr];
#pragma unroll
    for (int i = 0; i < 4; ++i)
#pragma unroll
        for (int j = 0; j < 4; ++j)
#pragma unroll
            for (int r = 0; r < 4; ++r) {
                int m = m0 + wm + i * 16 + kg * 4 + r;
                int n = n0 + wn + j * 16 + fr;
                out[(size_t)m * 1024 + n] = acc[i][j][r] + bj[j];
            }
}

__global__ void ws_fail(float* out, float wssz) {
    out[0] = -12345.0f;
    out[1] = wssz;
}

extern "C" void kernel_launch(void* const* d_in, const int* in_sizes, int n_in,
                              void* d_out, int out_size, void* d_ws, size_t ws_size,
                              hipStream_t stream) {
    (void)in_sizes; (void)n_in; (void)out_size;
    float* out = (float*)d_out;
    if (ws_size < WS_NEED) {                 // sentinel: reports ws_size via validation mismatch
        ws_fail<<<1, 1, 0, stream>>>(out, (float)ws_size);
        return;
    }

    const float* u    = (const float*)d_in[0];
    const float* in_w = (const float*)d_in[1];
    const float* in_b = (const float*)d_in[2];
    const float* kern = (const float*)d_in[3];
    const float* dmat = (const float*)d_in[4];
    const float* outw = (const float*)d_in[5];
    const float* outb = (const float*)d_in[6];

    char* ws = (char*)d_ws;
    float*          xT = (float*)(ws + XT_OFF);
    float2*         Xf = (float2*)(ws + XF_OFF);
    unsigned short* y  = (unsigned short*)(ws + Y_OFF);

    gemm_in_mfma<<<dim3(8, 64), TPB, 0, stream>>>(u, in_w, in_b, xT);
    fft_fwd<<<dim3(2048), TPB, 0, stream>>>(xT, Xf);
    conv_fused<<<dim3(4096), TPB, 0, stream>>>(kern, Xf, xT, dmat, y);
    gemm_out_mfma<<<dim3(64, 8), TPB, 0, stream>>>(y, outw, outb, out);
}